// Round 1
// baseline (370.772 us; speedup 1.0000x reference)
//
#include <hip/hip_runtime.h>

#define T_STEPS 2000
#define F_DIM   128
#define TILE    128
#define NTILES  16   // ceil(2000/128): 15 full tiles + one of 80

__device__ __forceinline__ float group32_reduce(float p) {
  // reduce across the 32-lane half-wave (masks <32 stay within the group)
#pragma unroll
  for (int m = 16; m >= 1; m >>= 1) p += __shfl_xor(p, m, 64);
  return p;
}

__global__ __launch_bounds__(256, 1) void lif_fused(
    const float* __restrict__ x, const float* __restrict__ W,
    const float* __restrict__ bias, float* __restrict__ out, int B) {
  const float BETA = 0.8807970779778823f;  // sigmoid(2.0), rounds to same f32
  const float VTH  = 1.0f;

  const int b      = blockIdx.x;
  const int tid    = threadIdx.x;
  const int lane   = tid & 63;
  const int wave   = tid >> 6;
  const int fgrp   = tid & 31;   // which float4 of the 128 features
  const int rowoff = tid >> 5;   // 0..7: row within a load round

  __shared__ float curbuf[2][TILE];

  const float4* xb = (const float4*)(x + (size_t)b * T_STEPS * F_DIM); // [2000][32] float4
  const float4  w4 = ((const float4*)W)[fgrp];
  const float   bs = bias[0];
  float* outb = out + (size_t)b * T_STEPS;

  float4 xv[16];
  float  v = 0.0f;

  auto load_tile = [&](int c) {
    const int base = c * TILE;
#pragma unroll
    for (int r = 0; r < 16; ++r) {
      const int row = base + r * 8 + rowoff;
      if (row < T_STEPS) xv[r] = xb[row * 32 + fgrp];
      else               xv[r] = make_float4(0.f, 0.f, 0.f, 0.f);
    }
  };

  auto reduce_tile = [&](int c) {
    const int base = c * TILE;
    float* wb = curbuf[c & 1];
#pragma unroll
    for (int r = 0; r < 16; ++r) {
      float p = xv[r].x * w4.x;
      p = fmaf(xv[r].y, w4.y, p);
      p = fmaf(xv[r].z, w4.z, p);
      p = fmaf(xv[r].w, w4.w, p);
      p = group32_reduce(p);
      if (fgrp == 0) {
        const int row = base + r * 8 + rowoff;
        if (row < T_STEPS) wb[r * 8 + rowoff] = p + bs;
      }
    }
  };

  // Prologue: tile 0 -> curbuf[0]
  load_tile(0);
  reduce_tile(0);
  __syncthreads();

  for (int c = 0; c < NTILES; ++c) {
    // Issue next tile's global loads first so they stream during the scan.
    if (c + 1 < NTILES) load_tile(c + 1);

    if (wave == 0) {
      // Redundant scan across all 64 lanes of wave 0; lane t&63 owns spike(t).
      const float* cb   = curbuf[c & 1];
      const int    base = c * TILE;
      const int    tlen = (T_STEPS - base < TILE) ? (T_STEPS - base) : TILE;
      float sp0 = 0.f, sp1 = 0.f;
      float cv[32], cn[32];
#pragma unroll
      for (int q = 0; q < 8; ++q)
        *(float4*)&cv[q * 4] = *(const float4*)&cb[q * 4];

      if (tlen == TILE) {
#pragma unroll
        for (int g = 0; g < 4; ++g) {
          if (g < 3) {  // prefetch next 32 cur values (broadcast LDS reads)
#pragma unroll
            for (int q = 0; q < 8; ++q)
              *(float4*)&cn[q * 4] = *(const float4*)&cb[(g + 1) * 32 + q * 4];
          }
#pragma unroll
          for (int j = 0; j < 32; ++j) {
            const int t = g * 32 + j;
            // match np elementwise semantics: mul then add, no contraction
            v = __fadd_rn(__fmul_rn(BETA, v), cv[j]);
            const float d = v - VTH;
            const float s = (d >= 0.f) ? 1.f : 0.f;
            v = (d >= 0.f) ? d : v;  // subtraction reset, same rounding as ref
            if (lane == (t & 63)) { if (t < 64) sp0 = s; else sp1 = s; }
          }
          if (g < 3) {
#pragma unroll
            for (int j = 0; j < 32; ++j) cv[j] = cn[j];
          }
        }
      } else {
        // Tail tile (tlen == 80): bounded, no prefetch (runs once).
#pragma unroll
        for (int g = 0; g < 4; ++g) {
          if (g * 32 < tlen) {
            if (g > 0) {
#pragma unroll
              for (int q = 0; q < 8; ++q)
                *(float4*)&cv[q * 4] = *(const float4*)&cb[g * 32 + q * 4];
            }
#pragma unroll
            for (int j = 0; j < 32; ++j) {
              const int  t     = g * 32 + j;
              const bool valid = (t < tlen);
              float vn = __fadd_rn(__fmul_rn(BETA, v), cv[j]);
              const float d = vn - VTH;
              const float s = (d >= 0.f) ? 1.f : 0.f;
              vn = (d >= 0.f) ? d : vn;
              if (valid) {
                v = vn;
                if (lane == (t & 63)) { if (t < 64) sp0 = s; else sp1 = s; }
              }
            }
          }
        }
      }
      // Coalesced 64-lane spike stores.
      if (lane < tlen)      outb[base + lane]      = sp0;
      if (64 + lane < tlen) outb[base + 64 + lane] = sp1;
    }

    if (c + 1 < NTILES) reduce_tile(c + 1);
    __syncthreads();
  }

  if (tid == 0) out[(size_t)B * T_STEPS + b] = v;  // final Vmem
}

extern "C" void kernel_launch(void* const* d_in, const int* in_sizes, int n_in,
                              void* d_out, int out_size, void* d_ws, size_t ws_size,
                              hipStream_t stream) {
  const float* x    = (const float*)d_in[0];
  const float* W    = (const float*)d_in[1];
  const float* bias = (const float*)d_in[2];
  float* out = (float*)d_out;
  const int B = in_sizes[0] / (T_STEPS * F_DIM);  // 256
  lif_fused<<<dim3(B), dim3(256), 0, stream>>>(x, W, bias, out, B);
}